// Round 1
// baseline (1484.930 us; speedup 1.0000x reference)
//
#include <hip/hip_runtime.h>
#include <cstdint>
#include <cstddef>

// Pipeline: cvt(Wqkv), cvt(Wdense) -> gemm_bt<fp32A,bias> (QKV) -> rope_scatter
//           -> flash attn (bf16 MFMA, online softmax) -> gemm_bt<bf16A> (dense)
// Sizes: S=2048 B=2 H=4096 NH=32 NG=2 HD=128 ROT=64, OQKV=4608
// Row index everywhere: row = s*B + b (matches (S,B,H) flattening).

#define S_LEN 2048
#define BATCH 2
#define NHEADS 32
#define NGROUPS 2
#define HEADDIM 128
#define OQKV 4608

typedef __attribute__((ext_vector_type(4))) float f32x4;
typedef __attribute__((ext_vector_type(4))) unsigned int u32x4;
typedef __attribute__((ext_vector_type(8))) unsigned short u16x8;
typedef __attribute__((ext_vector_type(8))) short s16x8;

union B8 { u32x4 q; u16x8 u; s16x8 s; };

__device__ __forceinline__ unsigned short f2b(float f) {
  unsigned int u = __builtin_bit_cast(unsigned int, f);
  u += 0x7fffu + ((u >> 16) & 1u);
  return (unsigned short)(u >> 16);
}

// fp32 -> bf16, 8 elems/thread, grid sized exactly
__global__ __launch_bounds__(256) void cvt_kernel(const float* __restrict__ in,
                                                  unsigned short* __restrict__ out) {
  size_t i = (size_t)blockIdx.x * 256 + threadIdx.x;
  const f32x4* p = (const f32x4*)(in + i * 8);
  f32x4 a = p[0], b = p[1];
  B8 r;
  r.u[0] = f2b(a[0]); r.u[1] = f2b(a[1]); r.u[2] = f2b(a[2]); r.u[3] = f2b(a[3]);
  r.u[4] = f2b(b[0]); r.u[5] = f2b(b[1]); r.u[6] = f2b(b[2]); r.u[7] = f2b(b[3]);
  *(u32x4*)(out + i * 8) = r.q;
}

// C[M,N] = A[M,K] * Bt[N,K]^T (+bias). 128x128 tile, 256 threads (4 waves),
// each wave a 64x64 quadrant as 4x4 16x16x32 bf16 MFMA frags.
// LDS rows padded to 40 elems (80B): keeps b128 16B-aligned, 2-way banks (free).
template<int A_FP32, int HAS_BIAS>
__global__ __launch_bounds__(256) void gemm_bt(const void* __restrict__ Ap,
                                               const unsigned short* __restrict__ Bt,
                                               const float* __restrict__ bias,
                                               float* __restrict__ C,
                                               int M, int N, int K) {
  __shared__ __align__(16) unsigned short lA[128 * 40];
  __shared__ __align__(16) unsigned short lB[128 * 40];
  const int tid = threadIdx.x;
  const int wave = tid >> 6, lane = tid & 63;
  const int quad = lane >> 4, l15 = lane & 15;
  const int m0 = blockIdx.y * 128, n0 = blockIdx.x * 128;
  const int wm = (wave & 1) * 64, wn = (wave >> 1) * 64;
  const int sr = tid >> 2, sc = (tid & 3) * 8;
  f32x4 acc[4][4] = {};
  const unsigned short* Ab = (const unsigned short*)Ap;
  const float* Af = (const float*)Ap;
  for (int k0 = 0; k0 < K; k0 += 32) {
    B8 a0, a1;
    u32x4 b0, b1;
    if (A_FP32) {
      const f32x4* p0 = (const f32x4*)(Af + (size_t)(m0 + sr) * K + k0 + sc);
      const f32x4* p1 = (const f32x4*)(Af + (size_t)(m0 + sr + 64) * K + k0 + sc);
      f32x4 x0 = p0[0], x1 = p0[1], y0 = p1[0], y1 = p1[1];
      for (int e = 0; e < 4; ++e) {
        a0.u[e] = f2b(x0[e]); a0.u[e + 4] = f2b(x1[e]);
        a1.u[e] = f2b(y0[e]); a1.u[e + 4] = f2b(y1[e]);
      }
    } else {
      a0.q = *(const u32x4*)(Ab + (size_t)(m0 + sr) * K + k0 + sc);
      a1.q = *(const u32x4*)(Ab + (size_t)(m0 + sr + 64) * K + k0 + sc);
    }
    b0 = *(const u32x4*)(Bt + (size_t)(n0 + sr) * K + k0 + sc);
    b1 = *(const u32x4*)(Bt + (size_t)(n0 + sr + 64) * K + k0 + sc);
    __syncthreads();
    *(u32x4*)(lA + sr * 40 + sc) = a0.q;
    *(u32x4*)(lA + (sr + 64) * 40 + sc) = a1.q;
    *(u32x4*)(lB + sr * 40 + sc) = b0;
    *(u32x4*)(lB + (sr + 64) * 40 + sc) = b1;
    __syncthreads();
    B8 af[4], bf[4];
    for (int i = 0; i < 4; ++i)
      af[i].q = *(const u32x4*)(lA + (wm + 16 * i + l15) * 40 + quad * 8);
    for (int j = 0; j < 4; ++j)
      bf[j].q = *(const u32x4*)(lB + (wn + 16 * j + l15) * 40 + quad * 8);
    for (int i = 0; i < 4; ++i)
      for (int j = 0; j < 4; ++j)
        acc[i][j] = __builtin_amdgcn_mfma_f32_16x16x32_bf16(af[i].s, bf[j].s, acc[i][j], 0, 0, 0);
  }
  for (int i = 0; i < 4; ++i) {
    int gm = m0 + wm + 16 * i + quad * 4;
    for (int j = 0; j < 4; ++j) {
      int gn = n0 + wn + 16 * j + l15;
      float bb = HAS_BIAS ? bias[gn] : 0.0f;
      for (int r = 0; r < 4; ++r)
        C[(size_t)(gm + r) * N + gn] = acc[i][j][r] + bb;
    }
  }
}

// mixed (4096 x 4608 fp32) -> rope'd q/k + v, bf16, layout [b][head][s][hd]
__global__ __launch_bounds__(256) void rope_scatter(const float* __restrict__ mixed,
                                                    const float* __restrict__ rope,
                                                    unsigned short* __restrict__ qb,
                                                    unsigned short* __restrict__ kb,
                                                    unsigned short* __restrict__ vb) {
  unsigned int idx = blockIdx.x * 256 + threadIdx.x;   // pair index, exact grid
  unsigned int row = idx / 2304;
  unsigned int pr = idx - row * 2304;
  unsigned int o = pr * 2;
  unsigned int s = row >> 1, b = row & 1;
  const float* mp = mixed + (size_t)row * OQKV + o;
  float x0 = mp[0], x1 = mp[1];
  unsigned short* dst;
  unsigned int d;
  bool do_rope;
  if (o < 4096) {
    unsigned int h = o >> 7; d = o & 127;
    dst = qb + (((size_t)(b * NHEADS + h) * S_LEN + s) * HEADDIM + d);
    do_rope = (d < 64);
  } else if (o < 4352) {
    unsigned int g = (o - 4096) >> 7; d = (o - 4096) & 127;
    dst = kb + (((size_t)(b * NGROUPS + g) * S_LEN + s) * HEADDIM + d);
    do_rope = (d < 64);
  } else {
    unsigned int g = (o - 4352) >> 7; d = (o - 4352) & 127;
    dst = vb + (((size_t)(b * NGROUPS + g) * S_LEN + s) * HEADDIM + d);
    do_rope = false;
  }
  if (do_rope) {
    unsigned int i = d >> 1;
    float c = rope[s * 64 + i * 2], sn = rope[s * 64 + i * 2 + 1];
    float y0 = x0 * c - x1 * sn;
    float y1 = x1 * c + x0 * sn;
    x0 = y0; x1 = y1;
  }
  dst[0] = f2b(x0);
  dst[1] = f2b(x1);
}

// Flash attention: block = (qtile 64 rows, head, batch), 4 waves x 16 Q-rows.
// 32-key tiles; QK^T and PV via 16x16x32 bf16 MFMA; online softmax in C-layout
// (row = quad*4+reg, col = lane&15); P transposed to A-layout via LDS.
__global__ __launch_bounds__(256) void attn_kernel(const unsigned short* __restrict__ qb,
                                                   const unsigned short* __restrict__ kb,
                                                   const unsigned short* __restrict__ vb,
                                                   unsigned short* __restrict__ ctx) {
  __shared__ __align__(16) unsigned short lv[128 * 40];      // V^T tile [hd][key]
  __shared__ __align__(16) unsigned short lp[4][16 * 40];    // per-wave P [q][key]
  const int qt = blockIdx.x, h = blockIdx.y, b = blockIdx.z;
  const int g = h >> 4;   // NH/NG = 16
  const int tid = threadIdx.x;
  const int wave = tid >> 6, lane = tid & 63;
  const int quad = lane >> 4, l15 = lane & 15;
  const int q0 = qt * 64 + wave * 16;
  const unsigned short* qp =
      qb + ((size_t)(b * NHEADS + h) * S_LEN + q0 + l15) * HEADDIM + quad * 8;
  B8 aq[4];
  for (int c = 0; c < 4; ++c) aq[c].q = *(const u32x4*)(qp + 32 * c);
  const unsigned short* kbase = kb + (size_t)(b * NGROUPS + g) * S_LEN * HEADDIM;
  const unsigned short* vbase = vb + (size_t)(b * NGROUPS + g) * S_LEN * HEADDIM;
  f32x4 o[8] = {};
  float mrow[4] = {-1e30f, -1e30f, -1e30f, -1e30f};
  float lrow[4] = {0.f, 0.f, 0.f, 0.f};
  const float scale = 0.08838834764831845f;
  const int nkt = qt * 2 + 2;
  const int vkey = tid & 31, vh0 = (tid >> 5) * 16;
  for (int kt = 0; kt < nkt; ++kt) {
    const int k0 = kt * 32;
    f32x4 sfr[2] = {};
    for (int half = 0; half < 2; ++half) {
      const unsigned short* kp =
          kbase + (size_t)(k0 + half * 16 + l15) * HEADDIM + quad * 8;
      for (int c = 0; c < 4; ++c) {
        B8 bk; bk.q = *(const u32x4*)(kp + 32 * c);
        sfr[half] = __builtin_amdgcn_mfma_f32_16x16x32_bf16(aq[c].s, bk.s, sfr[half], 0, 0, 0);
      }
    }
    float pvv[2][4], alpha[4];
    for (int r = 0; r < 4; ++r) {
      int qq = q0 + quad * 4 + r;
      float v0 = sfr[0][r] * scale;
      float v1 = sfr[1][r] * scale;
      if (k0 + l15 > qq) v0 = -1e30f;
      if (k0 + 16 + l15 > qq) v1 = -1e30f;
      float tmax = fmaxf(v0, v1);
      tmax = fmaxf(tmax, __shfl_xor(tmax, 1));
      tmax = fmaxf(tmax, __shfl_xor(tmax, 2));
      tmax = fmaxf(tmax, __shfl_xor(tmax, 4));
      tmax = fmaxf(tmax, __shfl_xor(tmax, 8));
      float mnew = fmaxf(mrow[r], tmax);
      float a = __expf(mrow[r] - mnew);   // first tile: exp(-1e30-x) = 0
      float p0 = __expf(v0 - mnew);
      float p1 = __expf(v1 - mnew);
      float rs = p0 + p1;
      rs += __shfl_xor(rs, 1);
      rs += __shfl_xor(rs, 2);
      rs += __shfl_xor(rs, 4);
      rs += __shfl_xor(rs, 8);
      lrow[r] = lrow[r] * a + rs;
      mrow[r] = mnew;
      alpha[r] = a;
      pvv[0][r] = p0; pvv[1][r] = p1;
    }
    for (int j = 0; j < 8; ++j)
      for (int r = 0; r < 4; ++r) o[j][r] *= alpha[r];
    __syncthreads();   // all waves done reading lv/lp from previous tile
    for (int half = 0; half < 2; ++half)
      for (int r = 0; r < 4; ++r)
        lp[wave][(quad * 4 + r) * 40 + half * 16 + l15] = f2b(pvv[half][r]);
    {
      const u32x4* pv = (const u32x4*)(vbase + (size_t)(k0 + vkey) * HEADDIM + vh0);
      B8 v0, v1; v0.q = pv[0]; v1.q = pv[1];
      for (int e = 0; e < 8; ++e) lv[(vh0 + e) * 40 + vkey] = v0.u[e];
      for (int e = 0; e < 8; ++e) lv[(vh0 + 8 + e) * 40 + vkey] = v1.u[e];
    }
    __syncthreads();
    B8 pa; pa.q = *(const u32x4*)(&lp[wave][l15 * 40 + quad * 8]);
    for (int j = 0; j < 8; ++j) {
      B8 bv; bv.q = *(const u32x4*)(&lv[(16 * j + l15) * 40 + quad * 8]);
      o[j] = __builtin_amdgcn_mfma_f32_16x16x32_bf16(pa.s, bv.s, o[j], 0, 0, 0);
    }
  }
  float inv[4];
  for (int r = 0; r < 4; ++r) inv[r] = 1.0f / lrow[r];
  for (int j = 0; j < 8; ++j) {
    for (int r = 0; r < 4; ++r) {
      int s = q0 + quad * 4 + r;
      ctx[(size_t)(s * BATCH + b) * 4096 + (size_t)h * HEADDIM + 16 * j + l15] =
          f2b(o[j][r] * inv[r]);
    }
  }
}

extern "C" void kernel_launch(void* const* d_in, const int* in_sizes, int n_in,
                              void* d_out, int out_size, void* d_ws, size_t ws_size,
                              hipStream_t stream) {
  const float* hidden = (const float*)d_in[0];
  // d_in[1] = attention_mask (known causal, unused)
  const float* rope = (const float*)d_in[2];
  const float* Wqkv = (const float*)d_in[3];
  const float* bqkv = (const float*)d_in[4];
  const float* Wdense = (const float*)d_in[5];
  float* out = (float*)d_out;
  char* ws = (char*)d_ws;

  // workspace layout (aliased regions: q/k/v reuse Wqkv_b after GEMM1,
  // ctx reuses mixed after rope). Peak = 140 MB.
  unsigned short* Wqkv_b   = (unsigned short*)(ws);                 // 37,748,736 B
  unsigned short* Wdense_b = (unsigned short*)(ws + 37748736);      // 33,554,432 B
  float*          mixed    = (float*)(ws + 71303168);               // 75,497,472 B
  unsigned short* qbuf     = (unsigned short*)(ws);                 // 33,554,432 B
  unsigned short* kbuf     = (unsigned short*)(ws + 33554432);      //  2,097,152 B
  unsigned short* vbuf     = (unsigned short*)(ws + 35651584);      //  2,097,152 B
  unsigned short* ctxb     = (unsigned short*)(ws + 71303168);      // 33,554,432 B

  cvt_kernel<<<9216, 256, 0, stream>>>(Wqkv, Wqkv_b);      // 4608*4096 / 8 / 256
  cvt_kernel<<<8192, 256, 0, stream>>>(Wdense, Wdense_b);  // 4096*4096 / 8 / 256

  gemm_bt<1, 1><<<dim3(36, 32), 256, 0, stream>>>(hidden, Wqkv_b, bqkv, mixed,
                                                  4096, 4608, 4096);
  rope_scatter<<<36864, 256, 0, stream>>>(mixed, rope, qbuf, kbuf, vbuf);
  attn_kernel<<<dim3(32, 32, 2), 256, 0, stream>>>(qbuf, kbuf, vbuf, ctxb);
  gemm_bt<0, 0><<<dim3(32, 32), 256, 0, stream>>>(ctxb, Wdense_b, nullptr, out,
                                                  4096, 4096, 4096);
}